// Round 1
// baseline (1060.750 us; speedup 1.0000x reference)
//
#include <hip/hip_runtime.h>
#include <hip/hip_bf16.h>
#include <cstdint>
#include <cstddef>

// Problem dims (fixed by setup_inputs)
#define TDIM 2048
#define HDIM 4096
#define MDIM 14336

typedef __attribute__((ext_vector_type(8))) __bf16 bf16x8;
typedef __attribute__((ext_vector_type(4))) float f32x4;

__device__ __constant__ float NF4_LUT[16] = {
    -1.0f, -0.6961928009986877f, -0.5250730514526367f, -0.39491748809814453f,
    -0.28444138169288635f, -0.18477343022823334f, -0.09105003625154495f, 0.0f,
    0.07958029955625534f, 0.16093020141124725f, 0.24611230194568634f,
    0.33791524171829224f, 0.44070982933044434f, 0.5626170039176941f,
    0.7229568362236023f, 1.0f};

// ---------------------------------------------------------------- utilities
__device__ inline void g2l16(const void* g, void* l) {
  __builtin_amdgcn_global_load_lds(
      (const __attribute__((address_space(1))) unsigned int*)g,
      (__attribute__((address_space(3))) unsigned int*)l,
      16 /*bytes, literal*/, 0, 0);
}

// ------------------------------------------------------------ x f32 -> bf16
__global__ __launch_bounds__(256) void f32_to_bf16_k(
    const float* __restrict__ in, __hip_bfloat16* __restrict__ out, int n8) {
  for (int i = blockIdx.x * 256 + threadIdx.x; i < n8; i += gridDim.x * 256) {
    const float4* p = (const float4*)(in + (size_t)i * 8);
    float4 a = p[0], b = p[1];
    union { __hip_bfloat16 h[8]; int4 v; } u;
    u.h[0] = __float2bfloat16(a.x);
    u.h[1] = __float2bfloat16(a.y);
    u.h[2] = __float2bfloat16(a.z);
    u.h[3] = __float2bfloat16(a.w);
    u.h[4] = __float2bfloat16(b.x);
    u.h[5] = __float2bfloat16(b.y);
    u.h[6] = __float2bfloat16(b.z);
    u.h[7] = __float2bfloat16(b.w);
    *(int4*)(out + (size_t)i * 8) = u.v;
  }
}

// --------------------------------------------------- NF4 dequant -> bf16 W
// codes: [N, K] int32 in [0,16); absmax: [N, K/64]; W: [N, K] bf16
__global__ __launch_bounds__(256) void dequant_nf4_k(
    const int* __restrict__ codes, const float* __restrict__ absmax,
    __hip_bfloat16* __restrict__ W, int K) {
  __shared__ float lut[16];
  if (threadIdx.x < 16) lut[threadIdx.x] = NF4_LUT[threadIdx.x];
  __syncthreads();
  const int row = blockIdx.x;
  const int K8 = K >> 3;
  const size_t rbase = (size_t)row * K;
  for (int c8 = threadIdx.x; c8 < K8; c8 += 256) {
    const int col = c8 << 3;
    const float am = absmax[(size_t)row * (K >> 6) + (col >> 6)];
    const int4* cp = (const int4*)(codes + rbase + col);
    int4 ca = cp[0], cb = cp[1];
    union { __hip_bfloat16 h[8]; int4 v; } u;
    u.h[0] = __float2bfloat16(lut[ca.x & 15] * am);
    u.h[1] = __float2bfloat16(lut[ca.y & 15] * am);
    u.h[2] = __float2bfloat16(lut[ca.z & 15] * am);
    u.h[3] = __float2bfloat16(lut[ca.w & 15] * am);
    u.h[4] = __float2bfloat16(lut[cb.x & 15] * am);
    u.h[5] = __float2bfloat16(lut[cb.y & 15] * am);
    u.h[6] = __float2bfloat16(lut[cb.z & 15] * am);
    u.h[7] = __float2bfloat16(lut[cb.w & 15] * am);
    *(int4*)(W + rbase + col) = u.v;
  }
}

// ------------------------------------------------------------------- GEMM
// C[M,N] = A[M,K] @ B[N,K]^T   (NT, bf16 in, f32 acc)
// 128x128 tile, BK=64, 4 waves (2x2), 16x16x32 MFMA (m97 structure).
// LDS XOR-swizzle (colb ^= (row&7)<<4) applied on BOTH global source (stage)
// and LDS read (rule #21: both-sides-or-neither with global_load_lds).
// EPI: 0 = store bf16 (gate); 1 = h = silu(G)*acc, store bf16 in-place;
//      2 = store f32 (down / final output)
template <int EPI>
__global__ __launch_bounds__(256, 2) void gemm_nt_k(
    const __hip_bfloat16* __restrict__ A, const __hip_bfloat16* __restrict__ B,
    void* __restrict__ Cv, const __hip_bfloat16* __restrict__ Gin,
    int M, int N, int K) {
  __shared__ __align__(16) char sA[128 * 128];
  __shared__ __align__(16) char sB[128 * 128];

  const int tid = threadIdx.x;
  const int lane = tid & 63;
  const int wid = tid >> 6;

  // bijective XCD swizzle (all our grids are %8 == 0)
  const int nbn = N >> 7;
  const int nwg = (M >> 7) * nbn;
  const int cpx = nwg >> 3;
  const int bid = blockIdx.x;
  const int wg = (bid & 7) * cpx + (bid >> 3);
  const int bm = wg / nbn, bn = wg % nbn;

  // ---- staging geometry: 8-row chunks of [row][128B], 16B/lane
  const int srow = lane >> 3;                       // row within 8-row chunk
  const int scolb = ((lane & 7) ^ srow) << 4;       // pre-swizzled global col
  const char* gA = (const char*)A +
      ((size_t)(bm * 128 + wid * 8 + srow) * K) * 2 + scolb;
  const char* gB = (const char*)B +
      ((size_t)(bn * 128 + wid * 8 + srow) * K) * 2 + scolb;
  const size_t cstep = (size_t)64 * K;              // +32 rows, in bytes
  char* lA = sA + wid * 1024;                       // wave-uniform LDS bases
  char* lB = sB + wid * 1024;

  // ---- fragment read offsets (swizzled): row*128 + (colb ^ ((row&7)<<4))
  const int wm = wid >> 1, wn = wid & 1;
  const int colsw = (((lane >> 4) << 4) ^ ((lane & 7) << 4));
  const int aoff = (wm * 64 + (lane & 15)) * 128 + colsw;
  const int boff = (wn * 64 + (lane & 15)) * 128 + colsw;

  f32x4 acc[4][4] = {};

  const int nk = K >> 6;
  for (int kt = 0; kt < nk; ++kt) {
    const char* pa = gA + (size_t)kt * 128;
    const char* pb = gB + (size_t)kt * 128;
#pragma unroll
    for (int c = 0; c < 4; ++c) {
      g2l16(pa + c * cstep, lA + c * 4096);
      g2l16(pb + c * cstep, lB + c * 4096);
    }
    __syncthreads();  // vmcnt drained before barrier -> tiles visible
#pragma unroll
    for (int ks = 0; ks < 2; ++ks) {
      bf16x8 af[4], bfr[4];
#pragma unroll
      for (int i = 0; i < 4; ++i) {
        af[i] = *(const bf16x8*)(sA + ((aoff + i * 2048) ^ (ks << 6)));
        bfr[i] = *(const bf16x8*)(sB + ((boff + i * 2048) ^ (ks << 6)));
      }
#pragma unroll
      for (int mi = 0; mi < 4; ++mi)
#pragma unroll
        for (int nj = 0; nj < 4; ++nj)
          acc[mi][nj] = __builtin_amdgcn_mfma_f32_16x16x32_bf16(
              af[mi], bfr[nj], acc[mi][nj], 0, 0, 0);
    }
    __syncthreads();  // all waves done reading before next-stage overwrite
  }

  // ---- epilogue: C/D layout col=lane&15, row=(lane>>4)*4+reg
  const int row0 = bm * 128 + wm * 64 + ((lane >> 4) << 2);
  const int col0 = bn * 128 + wn * 64 + (lane & 15);
#pragma unroll
  for (int mi = 0; mi < 4; ++mi) {
#pragma unroll
    for (int nj = 0; nj < 4; ++nj) {
#pragma unroll
      for (int r = 0; r < 4; ++r) {
        const size_t idx =
            (size_t)(row0 + mi * 16 + r) * N + (col0 + nj * 16);
        const float v = acc[mi][nj][r];
        if (EPI == 0) {
          ((__hip_bfloat16*)Cv)[idx] = __float2bfloat16(v);
        } else if (EPI == 1) {
          const float g = __bfloat162float(Gin[idx]);
          const float h = g / (1.0f + __expf(-g)) * v;  // silu(g) * u
          ((__hip_bfloat16*)Cv)[idx] = __float2bfloat16(h);
        } else {
          ((float*)Cv)[idx] = v;
        }
      }
    }
  }
}

// ---------------------------------------------------------------- launcher
extern "C" void kernel_launch(void* const* d_in, const int* in_sizes, int n_in,
                              void* d_out, int out_size, void* d_ws,
                              size_t ws_size, hipStream_t stream) {
  const float* x = (const float*)d_in[0];
  const int* gate_codes = (const int*)d_in[1];
  const float* gate_absmax = (const float*)d_in[2];
  const int* up_codes = (const int*)d_in[3];
  const float* up_absmax = (const float*)d_in[4];
  const int* down_codes = (const int*)d_in[5];
  const float* down_absmax = (const float*)d_in[6];

  char* ws = (char*)d_ws;
  __hip_bfloat16* xb = (__hip_bfloat16*)ws;  // [T, hd] bf16: 16 MB
  __hip_bfloat16* Wb =
      (__hip_bfloat16*)(ws + (size_t)TDIM * HDIM * 2);  // [m, hd] bf16: 112 MB
  __hip_bfloat16* Hb =
      (__hip_bfloat16*)(ws + (size_t)TDIM * HDIM * 2 +
                        (size_t)MDIM * HDIM * 2);  // [T, m] bf16: 56 MB

  // 1) x -> bf16
  f32_to_bf16_k<<<2048, 256, 0, stream>>>(x, xb, (TDIM * HDIM) / 8);

  // 2) gate: dequant + GEMM (store g)
  dequant_nf4_k<<<MDIM, 256, 0, stream>>>(gate_codes, gate_absmax, Wb, HDIM);
  gemm_nt_k<0><<<(TDIM / 128) * (MDIM / 128), 256, 0, stream>>>(
      xb, Wb, Hb, nullptr, TDIM, MDIM, HDIM);

  // 3) up: dequant + GEMM (h = silu(g)*u, in place)
  dequant_nf4_k<<<MDIM, 256, 0, stream>>>(up_codes, up_absmax, Wb, HDIM);
  gemm_nt_k<1><<<(TDIM / 128) * (MDIM / 128), 256, 0, stream>>>(
      xb, Wb, Hb, Hb, TDIM, MDIM, HDIM);

  // 4) down: dequant + GEMM (f32 out)
  dequant_nf4_k<<<HDIM, 256, 0, stream>>>(down_codes, down_absmax, Wb, MDIM);
  gemm_nt_k<2><<<(TDIM / 128) * (HDIM / 128), 256, 0, stream>>>(
      Hb, Wb, (float*)d_out, nullptr, TDIM, HDIM, MDIM);
}